// Round 3
// baseline (389.209 us; speedup 1.0000x reference)
//
#include <hip/hip_runtime.h>
#include <cmath>

#define NN 50000
#define KK 15
#define DD 128
#define HH 64
#define NKE (NN * KK)

// ---------------------------------------------------------------------------
// kP: ws[seg][row][j] = x[row] @ W_seg   (seg0=ew1[0:128], seg1=ew1[128:256],
// seg2=dw1[0:128]).  Block = 256 thr = 4 waves; block stages 32 x-rows into
// LDS ONCE (coalesced), then 3 segment passes.  Wave handles 8 rows, lane=j.
//   x : LDS uniform-broadcast ds_read_b128 (free)        [was: sK$ thrash]
//   W : lane-consecutive dword loads (L1/L2-resident)
//   out: lane-coalesced dword stores (full lines)
// ---------------------------------------------------------------------------
__global__ __launch_bounds__(256) void kP(const float* __restrict__ x,
                                          const float* __restrict__ ew1,
                                          const float* __restrict__ dw1,
                                          float* __restrict__ ws) {
    __shared__ float xs[32 * 128];          // 16 KB
    int tid = threadIdx.x;
    int rb = blockIdx.x * 32;
    int nrow = NN - rb; if (nrow > 32) nrow = 32;
    {   // coalesced stage: nrow*32 float4
        const float4* xg = (const float4*)(x + (size_t)rb * DD);
        float4* xs4 = (float4*)xs;
        int nf4 = nrow * 32;
#pragma unroll
        for (int i = 0; i < 4; ++i) {
            int fi = i * 256 + tid;
            if (fi < nf4) xs4[fi] = xg[fi];
        }
    }
    __syncthreads();

    int lane = tid & 63;
    int wv = tid >> 6;
    int r0 = rb + wv * 8;
    if (r0 >= NN) return;                   // no barriers after this point

#pragma unroll 1
    for (int seg = 0; seg < 3; ++seg) {
        const float* W = (seg == 0) ? ew1 : (seg == 1) ? (ew1 + DD * HH) : dw1;
        float acc[8];
#pragma unroll
        for (int r = 0; r < 8; ++r) acc[r] = 0.f;

#pragma unroll 1
        for (int i4 = 0; i4 < DD / 4; ++i4) {
            float w0 = W[(i4 * 4 + 0) * HH + lane];
            float w1 = W[(i4 * 4 + 1) * HH + lane];
            float w2 = W[(i4 * 4 + 2) * HH + lane];
            float w3 = W[(i4 * 4 + 3) * HH + lane];
#pragma unroll
            for (int r = 0; r < 8; ++r) {
                float4 xv = *(const float4*)&xs[(wv * 8 + r) * 128 + i4 * 4];
                acc[r] = fmaf(xv.x, w0, acc[r]);
                acc[r] = fmaf(xv.y, w1, acc[r]);
                acc[r] = fmaf(xv.z, w2, acc[r]);
                acc[r] = fmaf(xv.w, w3, acc[r]);
            }
        }
        float* o = ws + (size_t)seg * NN * HH + (size_t)r0 * HH + lane;
#pragma unroll
        for (int r = 0; r < 8; ++r)
            if (r0 + r < NN) o[r * HH] = acc[r];     // coalesced
    }
}

// ---------------------------------------------------------------------------
// kE: wave-per-node.  Lane j holds ew2 column j in 64 VGPRs (loaded once per
// wave, reused across ~8 nodes x 15 edges).  Per edge: ONE coalesced 256 B
// XB gather (lane=i), h shared via 64-float LDS round-trip (write 2/bank
// free, read uniform broadcast), 64 FMAs into a scalar acc, butterfly logit
// reduction.  XA kept in 1 VGPR for all 15 edges; next XB prefetched.
// ---------------------------------------------------------------------------
#define KE_WAVES (1536 * 4)
__global__ __launch_bounds__(256, 4) void kE(const int* __restrict__ srcIdx,
                                             const float* __restrict__ dist,
                                             const float* __restrict__ ws,
                                             const float* __restrict__ ew1,
                                             const float* __restrict__ eb1,
                                             const float* __restrict__ ew2,
                                             const float* __restrict__ eb2,
                                             const float* __restrict__ ew3,
                                             const float* __restrict__ eb3,
                                             float* __restrict__ energy_out) {
    __shared__ float hbuf[4 * 64];
    int lane = threadIdx.x & 63;
    int wv = threadIdx.x >> 6;
    float* hb = hbuf + wv * 64;
    const float* XA = ws;
    const float* XB = ws + (size_t)NN * HH;

    float w2col[64];
#pragma unroll
    for (int k = 0; k < 64; ++k) w2col[k] = ew2[k * HH + lane];
    float w1l_l = ew1[2 * DD * HH + lane];
    float eb1_l = eb1[lane];
    float eb2_l = eb2[lane];
    float ew3_l = ew3[lane];
    float eb3s = eb3[0];

    int wgid = blockIdx.x * 4 + wv;
#pragma unroll 1
    for (int n = wgid; n < NN; n += KE_WAVES) {
        float XAv = XA[(size_t)n * HH + lane];
        int sv = 0; float dv = 0.f;
        if (lane < KK) {
            sv = srcIdx[n * KK + lane];
            dv = dist[n * KK + lane];
        }
        float myE = 0.f;
        int s0 = __shfl(sv, 0);
        float xb = XB[(size_t)s0 * HH + lane];
#pragma unroll 1
        for (int e = 0; e < KK; ++e) {
            float d_e = __shfl(dv, e);
            float h = fmaxf(XAv + xb + d_e * w1l_l + eb1_l, 0.f);
            hb[lane] = h;
            if (e + 1 < KK) {                       // prefetch next gather
                int sn = __shfl(sv, e + 1);
                xb = XB[(size_t)sn * HH + lane];
            }
            float acc = 0.f;
#pragma unroll
            for (int k4 = 0; k4 < 16; ++k4) {
                float4 h4 = *(const float4*)(hb + k4 * 4);  // uniform bcast
                acc = fmaf(h4.x, w2col[k4 * 4 + 0], acc);
                acc = fmaf(h4.y, w2col[k4 * 4 + 1], acc);
                acc = fmaf(h4.z, w2col[k4 * 4 + 2], acc);
                acc = fmaf(h4.w, w2col[k4 * 4 + 3], acc);
            }
            float v = fmaxf(acc + eb2_l, 0.f) * ew3_l;
            v += __shfl_xor(v, 32);
            v += __shfl_xor(v, 16);
            v += __shfl_xor(v, 8);
            v += __shfl_xor(v, 4);
            v += __shfl_xor(v, 2);
            v += __shfl_xor(v, 1);
            float en = 1.f / (1.f + expf(-2.f * (v + eb3s)));
            if (lane == e) myE = en;
        }
        if (lane < KK) energy_out[n * KK + lane] = myE;
    }
}

// ---------------------------------------------------------------------------
// kF: thread-per-node.  dw2 staged in LDS (16 KB), jj-chunked acc[16] with
// layer-1 recomputed per chunk (cheap); only the 512 B uniform vectors stay
// on the scalar path (sK$-resident).  Sort/gate/normalize as before.
// ---------------------------------------------------------------------------
__global__ __launch_bounds__(256) void kF(const float* __restrict__ ws,
                                          const float* __restrict__ dw1,
                                          const float* __restrict__ db1,
                                          const float* __restrict__ dw2,
                                          const float* __restrict__ db2,
                                          const float* __restrict__ dw3,
                                          const float* __restrict__ db3,
                                          float* __restrict__ out) {
    __shared__ float w2s[HH * HH];          // 16 KB
    {
        const float4* g = (const float4*)dw2;
        float4* s4 = (float4*)w2s;
#pragma unroll
        for (int i = 0; i < 4; ++i)
            s4[i * 256 + threadIdx.x] = g[i * 256 + threadIdx.x];
    }
    __syncthreads();

    int n = blockIdx.x * 256 + threadIdx.x;
    if (n >= NN) return;
    const float* energy = out + 2 * (size_t)NKE;

    float ev[KK];
    float dh = 0.f;
#pragma unroll
    for (int j = 0; j < KK; ++j) {
        ev[j] = energy[(size_t)n * KK + j];
        dh += ev[j];
    }

    const float* XC = ws + 2 * (size_t)NN * HH + (size_t)n * HH;
    const float* w1l = dw1 + DD * HH;       // degree-hint row (256 B, sK$)
    float kraw = db3[0];

#pragma unroll 1
    for (int c = 0; c < 4; ++c) {
        float acc[16];
#pragma unroll
        for (int t = 0; t < 16; ++t) acc[t] = 0.f;
#pragma unroll 1
        for (int k4 = 0; k4 < 16; ++k4) {
            float4 cx = *(const float4*)(XC + k4 * 4);
            float cv[4] = {cx.x, cx.y, cx.z, cx.w};
#pragma unroll
            for (int m = 0; m < 4; ++m) {
                int k = k4 * 4 + m;
                float g = fmaxf(cv[m] + dh * w1l[k] + db1[k], 0.f);
                float4 wA = *(const float4*)&w2s[k * HH + c * 16 + 0];
                float4 wB = *(const float4*)&w2s[k * HH + c * 16 + 4];
                float4 wC = *(const float4*)&w2s[k * HH + c * 16 + 8];
                float4 wD = *(const float4*)&w2s[k * HH + c * 16 + 12];
                acc[0]  = fmaf(g, wA.x, acc[0]);  acc[1]  = fmaf(g, wA.y, acc[1]);
                acc[2]  = fmaf(g, wA.z, acc[2]);  acc[3]  = fmaf(g, wA.w, acc[3]);
                acc[4]  = fmaf(g, wB.x, acc[4]);  acc[5]  = fmaf(g, wB.y, acc[5]);
                acc[6]  = fmaf(g, wB.z, acc[6]);  acc[7]  = fmaf(g, wB.w, acc[7]);
                acc[8]  = fmaf(g, wC.x, acc[8]);  acc[9]  = fmaf(g, wC.y, acc[9]);
                acc[10] = fmaf(g, wC.z, acc[10]); acc[11] = fmaf(g, wC.w, acc[11]);
                acc[12] = fmaf(g, wD.x, acc[12]); acc[13] = fmaf(g, wD.y, acc[13]);
                acc[14] = fmaf(g, wD.z, acc[14]); acc[15] = fmaf(g, wD.w, acc[15]);
            }
        }
#pragma unroll
        for (int t = 0; t < 16; ++t)
            kraw = fmaf(fmaxf(acc[t] + db2[c * 16 + t], 0.f), dw3[c * 16 + t], kraw);
    }

    float kcont = 2.f + 13.f / (1.f + expf(-kraw));
    out[3 * (size_t)NKE + n] = kcont;

    // register-resident sort of (energy desc, idx asc), 16-wide network
    float se[16];
    int si[16];
#pragma unroll
    for (int j = 0; j < KK; ++j) { se[j] = ev[j]; si[j] = j; }
    se[15] = -1.f; si[15] = 15;

#pragma unroll
    for (int p = 1; p < 16; p <<= 1) {
#pragma unroll
        for (int k = p; k >= 1; k >>= 1) {
#pragma unroll
            for (int j = k & (p - 1); j + k < 16; j += 2 * k) {
#pragma unroll
                for (int i = 0; i < k; ++i) {
                    int a = i + j, b = i + j + k;
                    if (b < 16 && (a / (2 * p)) == (b / (2 * p))) {
                        bool sw = (se[b] > se[a]) ||
                                  (se[b] == se[a] && si[b] < si[a]);
                        float ea = sw ? se[b] : se[a];
                        float eb = sw ? se[a] : se[b];
                        int ia = sw ? si[b] : si[a];
                        int ib = sw ? si[a] : si[b];
                        se[a] = ea; se[b] = eb; si[a] = ia; si[b] = ib;
                    }
                }
            }
        }
    }

    float kint = rintf(kcont);
    kint = fminf(fmaxf(kint, 2.f), 15.f);

    float wsrt[KK];
    float denom = 0.f;
#pragma unroll
    for (int r = 0; r < KK; ++r) {
        float sel = ((float)(r + 1) <= kint) ? 1.f : 0.f;
        float wvv = se[r] * sel;
        wsrt[r] = wvv;
        denom += wvv;
    }
    denom = fmaxf(denom, 1e-12f);

#pragma unroll
    for (int r = 0; r < KK; ++r) {
        float sel = ((float)(r + 1) <= kint) ? 1.f : 0.f;
        int j0 = si[r];
        out[(size_t)NKE + (size_t)n * KK + j0] = sel;     // edge_gate
        out[(size_t)n * KK + j0] = wsrt[r] / denom;       // edge_weight
    }
}

extern "C" void kernel_launch(void* const* d_in, const int* in_sizes, int n_in,
                              void* d_out, int out_size, void* d_ws, size_t ws_size,
                              hipStream_t stream) {
    const float* x   = (const float*)d_in[0];
    const int*   ei  = (const int*)d_in[1];
    const float* ed  = (const float*)d_in[2];
    const float* ew1 = (const float*)d_in[3];
    const float* eb1 = (const float*)d_in[4];
    const float* ew2 = (const float*)d_in[5];
    const float* eb2 = (const float*)d_in[6];
    const float* ew3 = (const float*)d_in[7];
    const float* eb3 = (const float*)d_in[8];
    const float* dw1 = (const float*)d_in[9];
    const float* db1 = (const float*)d_in[10];
    const float* dw2 = (const float*)d_in[11];
    const float* db2 = (const float*)d_in[12];
    const float* dw3 = (const float*)d_in[13];
    const float* db3 = (const float*)d_in[14];
    float* out = (float*)d_out;
    float* ws  = (float*)d_ws;

    hipLaunchKernelGGL(kP, dim3((NN + 31) / 32), dim3(256), 0, stream,
                       x, ew1, dw1, ws);
    hipLaunchKernelGGL(kE, dim3(1536), dim3(256), 0, stream,
                       ei, ed, ws, ew1, eb1, ew2, eb2, ew3, eb3,
                       out + 2 * (size_t)NKE);
    hipLaunchKernelGGL(kF, dim3((NN + 255) / 256), dim3(256), 0, stream,
                       ws, dw1, db1, dw2, db2, dw3, db3, out);
}

// Round 4
// 272.245 us; speedup vs baseline: 1.4296x; 1.4296x over previous
//
#include <hip/hip_runtime.h>
#include <cmath>

#define NN 50000
#define KK 15
#define DD 128
#define HH 64
#define NKE (NN * KK)

// ---------------------------------------------------------------------------
// kP: fused 3-segment GEMM.  ws[seg][row][j] = x[row] @ W_seg for
// seg0=ew1[0:128], seg1=ew1[128:256], seg2=dw1[0:128] in ONE pass:
// each x ds_read_b128 feeds 12 FMAs (3 segs x 4 i) instead of 4.
// Wave = 8 rows x 64 cols (lane=j).  W: lane-coalesced vector loads
// (L2-hot).  Stores: lane-coalesced full lines.
// ---------------------------------------------------------------------------
__global__ __launch_bounds__(256) void kP(const float* __restrict__ x,
                                          const float* __restrict__ ew1,
                                          const float* __restrict__ dw1,
                                          float* __restrict__ ws) {
    __shared__ float xs[32 * 128];          // 16 KB
    int tid = threadIdx.x;
    int rb = blockIdx.x * 32;
    int nrow = NN - rb; if (nrow > 32) nrow = 32;
    {
        const float4* xg = (const float4*)(x + (size_t)rb * DD);
        float4* xs4 = (float4*)xs;
        int nf4 = nrow * 32;
#pragma unroll
        for (int i = 0; i < 4; ++i) {
            int fi = i * 256 + tid;
            if (fi < nf4) xs4[fi] = xg[fi];
        }
    }
    __syncthreads();

    int lane = tid & 63;
    int wv = tid >> 6;
    int r0 = rb + wv * 8;
    if (r0 >= NN) return;

    const float* W0 = ew1;
    const float* W1 = ew1 + DD * HH;
    const float* W2 = dw1;

    float a0[8], a1[8], a2[8];
#pragma unroll
    for (int r = 0; r < 8; ++r) { a0[r] = 0.f; a1[r] = 0.f; a2[r] = 0.f; }

#pragma unroll 1
    for (int i4 = 0; i4 < DD / 4; ++i4) {
        float w00 = W0[(i4 * 4 + 0) * HH + lane];
        float w01 = W0[(i4 * 4 + 1) * HH + lane];
        float w02 = W0[(i4 * 4 + 2) * HH + lane];
        float w03 = W0[(i4 * 4 + 3) * HH + lane];
        float w10 = W1[(i4 * 4 + 0) * HH + lane];
        float w11 = W1[(i4 * 4 + 1) * HH + lane];
        float w12 = W1[(i4 * 4 + 2) * HH + lane];
        float w13 = W1[(i4 * 4 + 3) * HH + lane];
        float w20 = W2[(i4 * 4 + 0) * HH + lane];
        float w21 = W2[(i4 * 4 + 1) * HH + lane];
        float w22 = W2[(i4 * 4 + 2) * HH + lane];
        float w23 = W2[(i4 * 4 + 3) * HH + lane];
#pragma unroll
        for (int r = 0; r < 8; ++r) {
            float4 xv = *(const float4*)&xs[(wv * 8 + r) * 128 + i4 * 4];
            a0[r] = fmaf(xv.x, w00, a0[r]);
            a0[r] = fmaf(xv.y, w01, a0[r]);
            a0[r] = fmaf(xv.z, w02, a0[r]);
            a0[r] = fmaf(xv.w, w03, a0[r]);
            a1[r] = fmaf(xv.x, w10, a1[r]);
            a1[r] = fmaf(xv.y, w11, a1[r]);
            a1[r] = fmaf(xv.z, w12, a1[r]);
            a1[r] = fmaf(xv.w, w13, a1[r]);
            a2[r] = fmaf(xv.x, w20, a2[r]);
            a2[r] = fmaf(xv.y, w21, a2[r]);
            a2[r] = fmaf(xv.z, w22, a2[r]);
            a2[r] = fmaf(xv.w, w23, a2[r]);
        }
    }
    float* o0 = ws + (size_t)r0 * HH + lane;
    float* o1 = ws + (size_t)NN * HH + (size_t)r0 * HH + lane;
    float* o2 = ws + 2 * (size_t)NN * HH + (size_t)r0 * HH + lane;
#pragma unroll
    for (int r = 0; r < 8; ++r)
        if (r0 + r < NN) {
            o0[r * HH] = a0[r];
            o1[r * HH] = a1[r];
            o2[r * HH] = a2[r];
        }
}

// ---------------------------------------------------------------------------
// kE: thread-per-edge (R2 structure, fixed).  acc[64] in VGPRs (1 edge only,
// no AGPR overflow), ew2 rows wave-uniform -> s_load on the scalar pipe
// (16 KB sK$/L2-hot), XA/XB gathered as float4 with next-iteration prefetch.
// ---------------------------------------------------------------------------
__global__ __launch_bounds__(128, 4) void kE(const int* __restrict__ srcIdx,
                                             const float* __restrict__ dist,
                                             const float* __restrict__ ws,
                                             const float* __restrict__ ew1,
                                             const float* __restrict__ eb1,
                                             const float* __restrict__ ew2,
                                             const float* __restrict__ eb2,
                                             const float* __restrict__ ew3,
                                             const float* __restrict__ eb3,
                                             float* __restrict__ energy_out) {
    int e = blockIdx.x * 128 + threadIdx.x;
    if (e >= NKE) return;
    int s = srcIdx[e];
    int d = e / KK;
    float dd = dist[e];
    const float* A = ws + (size_t)d * HH;
    const float* B = ws + (size_t)NN * HH + (size_t)s * HH;
    const float* w1l = ew1 + 2 * DD * HH;   // dist-weight row (256 B, uniform)

    float acc[HH];
#pragma unroll
    for (int j = 0; j < HH; ++j) acc[j] = 0.f;

    float4 a4 = *(const float4*)A;
    float4 b4 = *(const float4*)B;
#pragma unroll 1
    for (int i4 = 0; i4 < HH / 4; ++i4) {
        float4 a = a4, b = b4;
        int nx = (i4 + 1 < HH / 4) ? (i4 + 1) : i4;
        a4 = *(const float4*)(A + nx * 4);      // prefetch
        b4 = *(const float4*)(B + nx * 4);
        float h[4];
        h[0] = fmaxf(a.x + b.x + dd * w1l[i4 * 4 + 0] + eb1[i4 * 4 + 0], 0.f);
        h[1] = fmaxf(a.y + b.y + dd * w1l[i4 * 4 + 1] + eb1[i4 * 4 + 1], 0.f);
        h[2] = fmaxf(a.z + b.z + dd * w1l[i4 * 4 + 2] + eb1[i4 * 4 + 2], 0.f);
        h[3] = fmaxf(a.w + b.w + dd * w1l[i4 * 4 + 3] + eb1[i4 * 4 + 3], 0.f);
#pragma unroll
        for (int k = 0; k < 4; ++k) {
            const float* wr = ew2 + (i4 * 4 + k) * HH;   // uniform -> s_load
#pragma unroll
            for (int j4 = 0; j4 < 16; ++j4) {
                float4 w = *(const float4*)(wr + j4 * 4);
                acc[j4 * 4 + 0] = fmaf(h[k], w.x, acc[j4 * 4 + 0]);
                acc[j4 * 4 + 1] = fmaf(h[k], w.y, acc[j4 * 4 + 1]);
                acc[j4 * 4 + 2] = fmaf(h[k], w.z, acc[j4 * 4 + 2]);
                acc[j4 * 4 + 3] = fmaf(h[k], w.w, acc[j4 * 4 + 3]);
            }
        }
    }
    float lg = eb3[0];
#pragma unroll
    for (int j = 0; j < HH; ++j)
        lg = fmaf(fmaxf(acc[j] + eb2[j], 0.f), ew3[j], lg);
    energy_out[e] = 1.f / (1.f + expf(-2.f * lg));
}

// ---------------------------------------------------------------------------
// kF: thread-per-node, single-pass acc[64], weights via uniform global reads
// (s_load, 16 KB hot).  No LDS.  Register sort + hard gate + normalize.
// ---------------------------------------------------------------------------
__global__ __launch_bounds__(128, 1) void kF(const float* __restrict__ ws,
                                             const float* __restrict__ dw1,
                                             const float* __restrict__ db1,
                                             const float* __restrict__ dw2,
                                             const float* __restrict__ db2,
                                             const float* __restrict__ dw3,
                                             const float* __restrict__ db3,
                                             float* __restrict__ out) {
    int n = blockIdx.x * 128 + threadIdx.x;
    if (n >= NN) return;
    const float* energy = out + 2 * (size_t)NKE;

    float ev[KK];
    float dh = 0.f;
#pragma unroll
    for (int j = 0; j < KK; ++j) {
        ev[j] = energy[(size_t)n * KK + j];
        dh += ev[j];
    }

    const float* XC = ws + 2 * (size_t)NN * HH + (size_t)n * HH;
    const float* w1l = dw1 + DD * HH;       // degree-hint row (256 B, uniform)

    float acc[HH];
#pragma unroll
    for (int j = 0; j < HH; ++j) acc[j] = 0.f;

    float4 c4 = *(const float4*)XC;
#pragma unroll 1
    for (int i4 = 0; i4 < HH / 4; ++i4) {
        float4 c = c4;
        int nx = (i4 + 1 < HH / 4) ? (i4 + 1) : i4;
        c4 = *(const float4*)(XC + nx * 4);
        float cv[4] = {c.x, c.y, c.z, c.w};
#pragma unroll
        for (int m = 0; m < 4; ++m) {
            int k = i4 * 4 + m;
            float g = fmaxf(cv[m] + dh * w1l[k] + db1[k], 0.f);
            const float* wr = dw2 + k * HH;      // uniform -> s_load
#pragma unroll
            for (int j4 = 0; j4 < 16; ++j4) {
                float4 w = *(const float4*)(wr + j4 * 4);
                acc[j4 * 4 + 0] = fmaf(g, w.x, acc[j4 * 4 + 0]);
                acc[j4 * 4 + 1] = fmaf(g, w.y, acc[j4 * 4 + 1]);
                acc[j4 * 4 + 2] = fmaf(g, w.z, acc[j4 * 4 + 2]);
                acc[j4 * 4 + 3] = fmaf(g, w.w, acc[j4 * 4 + 3]);
            }
        }
    }
    float kraw = db3[0];
#pragma unroll
    for (int j = 0; j < HH; ++j)
        kraw = fmaf(fmaxf(acc[j] + db2[j], 0.f), dw3[j], kraw);

    float kcont = 2.f + 13.f / (1.f + expf(-kraw));
    out[3 * (size_t)NKE + n] = kcont;

    // register-resident sort of (energy desc, idx asc), 16-wide network
    float se[16];
    int si[16];
#pragma unroll
    for (int j = 0; j < KK; ++j) { se[j] = ev[j]; si[j] = j; }
    se[15] = -1.f; si[15] = 15;

#pragma unroll
    for (int p = 1; p < 16; p <<= 1) {
#pragma unroll
        for (int k = p; k >= 1; k >>= 1) {
#pragma unroll
            for (int j = k & (p - 1); j + k < 16; j += 2 * k) {
#pragma unroll
                for (int i = 0; i < k; ++i) {
                    int a = i + j, b = i + j + k;
                    if (b < 16 && (a / (2 * p)) == (b / (2 * p))) {
                        bool sw = (se[b] > se[a]) ||
                                  (se[b] == se[a] && si[b] < si[a]);
                        float ea = sw ? se[b] : se[a];
                        float eb = sw ? se[a] : se[b];
                        int ia = sw ? si[b] : si[a];
                        int ib = sw ? si[a] : si[b];
                        se[a] = ea; se[b] = eb; si[a] = ia; si[b] = ib;
                    }
                }
            }
        }
    }

    float kint = rintf(kcont);
    kint = fminf(fmaxf(kint, 2.f), 15.f);

    float wsrt[KK];
    float denom = 0.f;
#pragma unroll
    for (int r = 0; r < KK; ++r) {
        float sel = ((float)(r + 1) <= kint) ? 1.f : 0.f;
        float wvv = se[r] * sel;
        wsrt[r] = wvv;
        denom += wvv;
    }
    denom = fmaxf(denom, 1e-12f);

#pragma unroll
    for (int r = 0; r < KK; ++r) {
        float sel = ((float)(r + 1) <= kint) ? 1.f : 0.f;
        int j0 = si[r];
        out[(size_t)NKE + (size_t)n * KK + j0] = sel;     // edge_gate
        out[(size_t)n * KK + j0] = wsrt[r] / denom;       // edge_weight
    }
}

extern "C" void kernel_launch(void* const* d_in, const int* in_sizes, int n_in,
                              void* d_out, int out_size, void* d_ws, size_t ws_size,
                              hipStream_t stream) {
    const float* x   = (const float*)d_in[0];
    const int*   ei  = (const int*)d_in[1];
    const float* ed  = (const float*)d_in[2];
    const float* ew1 = (const float*)d_in[3];
    const float* eb1 = (const float*)d_in[4];
    const float* ew2 = (const float*)d_in[5];
    const float* eb2 = (const float*)d_in[6];
    const float* ew3 = (const float*)d_in[7];
    const float* eb3 = (const float*)d_in[8];
    const float* dw1 = (const float*)d_in[9];
    const float* db1 = (const float*)d_in[10];
    const float* dw2 = (const float*)d_in[11];
    const float* db2 = (const float*)d_in[12];
    const float* dw3 = (const float*)d_in[13];
    const float* db3 = (const float*)d_in[14];
    float* out = (float*)d_out;
    float* ws  = (float*)d_ws;

    hipLaunchKernelGGL(kP, dim3((NN + 31) / 32), dim3(256), 0, stream,
                       x, ew1, dw1, ws);
    hipLaunchKernelGGL(kE, dim3((NKE + 127) / 128), dim3(128), 0, stream,
                       ei, ed, ws, ew1, eb1, ew2, eb2, ew3, eb3,
                       out + 2 * (size_t)NKE);
    hipLaunchKernelGGL(kF, dim3((NN + 127) / 128), dim3(128), 0, stream,
                       ws, dw1, db1, dw2, db2, dw3, db3, out);
}

// Round 5
// 269.279 us; speedup vs baseline: 1.4454x; 1.0110x over previous
//
#include <hip/hip_runtime.h>
#include <cmath>

#define NN 50000
#define KK 15
#define DD 128
#define HH 64
#define NKE (NN * KK)

// ---------------------------------------------------------------------------
// kP: fused 3-segment per-node GEMM, NO LDS.
//   ws[0][row][j] = x[row] @ ew1[0:128]      (XA)
//   ws[1][row][j] = x[row] @ ew1[128:256]    (XB)
//   ws[2][row][j] = x[row] @ dw1[0:128]      (XC)
// Wave = 8 rows x 64 cols (lane=j).  x is read with wave-UNIFORM addresses
// (row id derived via readfirstlane) -> scalar/uniform broadcast path, NOT
// the LDS port (LDS b128 broadcast = 16B/12cyc was R4's kP bottleneck).
// Each x float4 feeds 12 FMAs (3 segs x 4).  W: lane-coalesced loads.
// Stores: lane-coalesced full lines.
// ---------------------------------------------------------------------------
__global__ __launch_bounds__(256) void kP(const float* __restrict__ x,
                                          const float* __restrict__ ew1,
                                          const float* __restrict__ dw1,
                                          float* __restrict__ ws) {
    int lane = threadIdx.x & 63;
    int wv = __builtin_amdgcn_readfirstlane((int)(threadIdx.x >> 6));
    int r0 = blockIdx.x * 32 + wv * 8;       // 50000 % 8 == 0: no intra-wave tail
    if (r0 >= NN) return;

    const float* W0 = ew1;
    const float* W1 = ew1 + DD * HH;
    const float* W2 = dw1;
    const float* xw = x + (size_t)r0 * DD;

    float a0[8], a1[8], a2[8];
#pragma unroll
    for (int r = 0; r < 8; ++r) { a0[r] = 0.f; a1[r] = 0.f; a2[r] = 0.f; }

#pragma unroll 1
    for (int i4 = 0; i4 < DD / 4; ++i4) {
        // 12 lane-coalesced W loads (3 segs x 4 rows of W)
        float w00 = W0[(i4 * 4 + 0) * HH + lane];
        float w01 = W0[(i4 * 4 + 1) * HH + lane];
        float w02 = W0[(i4 * 4 + 2) * HH + lane];
        float w03 = W0[(i4 * 4 + 3) * HH + lane];
        float w10 = W1[(i4 * 4 + 0) * HH + lane];
        float w11 = W1[(i4 * 4 + 1) * HH + lane];
        float w12 = W1[(i4 * 4 + 2) * HH + lane];
        float w13 = W1[(i4 * 4 + 3) * HH + lane];
        float w20 = W2[(i4 * 4 + 0) * HH + lane];
        float w21 = W2[(i4 * 4 + 1) * HH + lane];
        float w22 = W2[(i4 * 4 + 2) * HH + lane];
        float w23 = W2[(i4 * 4 + 3) * HH + lane];
#pragma unroll
        for (int r = 0; r < 8; ++r) {
            // wave-uniform address -> scalar broadcast, no LDS
            float4 xv = *(const float4*)(xw + r * DD + i4 * 4);
            a0[r] = fmaf(xv.x, w00, a0[r]);
            a0[r] = fmaf(xv.y, w01, a0[r]);
            a0[r] = fmaf(xv.z, w02, a0[r]);
            a0[r] = fmaf(xv.w, w03, a0[r]);
            a1[r] = fmaf(xv.x, w10, a1[r]);
            a1[r] = fmaf(xv.y, w11, a1[r]);
            a1[r] = fmaf(xv.z, w12, a1[r]);
            a1[r] = fmaf(xv.w, w13, a1[r]);
            a2[r] = fmaf(xv.x, w20, a2[r]);
            a2[r] = fmaf(xv.y, w21, a2[r]);
            a2[r] = fmaf(xv.z, w22, a2[r]);
            a2[r] = fmaf(xv.w, w23, a2[r]);
        }
    }
    float* o0 = ws + (size_t)r0 * HH + lane;
    float* o1 = ws + (size_t)NN * HH + (size_t)r0 * HH + lane;
    float* o2 = ws + 2 * (size_t)NN * HH + (size_t)r0 * HH + lane;
#pragma unroll
    for (int r = 0; r < 8; ++r) {
        o0[r * HH] = a0[r];
        o1[r * HH] = a1[r];
        o2[r * HH] = a2[r];
    }
}

// ---------------------------------------------------------------------------
// kE: thread-per-edge (unchanged from R4 — best measured: 93 us).
// acc[64] AGPR-backed, ew2 rows wave-uniform -> s_load, XA/XB float4 gather
// with next-iteration prefetch.
// ---------------------------------------------------------------------------
__global__ __launch_bounds__(128, 4) void kE(const int* __restrict__ srcIdx,
                                             const float* __restrict__ dist,
                                             const float* __restrict__ ws,
                                             const float* __restrict__ ew1,
                                             const float* __restrict__ eb1,
                                             const float* __restrict__ ew2,
                                             const float* __restrict__ eb2,
                                             const float* __restrict__ ew3,
                                             const float* __restrict__ eb3,
                                             float* __restrict__ energy_out) {
    int e = blockIdx.x * 128 + threadIdx.x;
    if (e >= NKE) return;
    int s = srcIdx[e];
    int d = e / KK;
    float dd = dist[e];
    const float* A = ws + (size_t)d * HH;
    const float* B = ws + (size_t)NN * HH + (size_t)s * HH;
    const float* w1l = ew1 + 2 * DD * HH;

    float acc[HH];
#pragma unroll
    for (int j = 0; j < HH; ++j) acc[j] = 0.f;

    float4 a4 = *(const float4*)A;
    float4 b4 = *(const float4*)B;
#pragma unroll 1
    for (int i4 = 0; i4 < HH / 4; ++i4) {
        float4 a = a4, b = b4;
        int nx = (i4 + 1 < HH / 4) ? (i4 + 1) : i4;
        a4 = *(const float4*)(A + nx * 4);
        b4 = *(const float4*)(B + nx * 4);
        float h[4];
        h[0] = fmaxf(a.x + b.x + dd * w1l[i4 * 4 + 0] + eb1[i4 * 4 + 0], 0.f);
        h[1] = fmaxf(a.y + b.y + dd * w1l[i4 * 4 + 1] + eb1[i4 * 4 + 1], 0.f);
        h[2] = fmaxf(a.z + b.z + dd * w1l[i4 * 4 + 2] + eb1[i4 * 4 + 2], 0.f);
        h[3] = fmaxf(a.w + b.w + dd * w1l[i4 * 4 + 3] + eb1[i4 * 4 + 3], 0.f);
#pragma unroll
        for (int k = 0; k < 4; ++k) {
            const float* wr = ew2 + (i4 * 4 + k) * HH;
#pragma unroll
            for (int j4 = 0; j4 < 16; ++j4) {
                float4 w = *(const float4*)(wr + j4 * 4);
                acc[j4 * 4 + 0] = fmaf(h[k], w.x, acc[j4 * 4 + 0]);
                acc[j4 * 4 + 1] = fmaf(h[k], w.y, acc[j4 * 4 + 1]);
                acc[j4 * 4 + 2] = fmaf(h[k], w.z, acc[j4 * 4 + 2]);
                acc[j4 * 4 + 3] = fmaf(h[k], w.w, acc[j4 * 4 + 3]);
            }
        }
    }
    float lg = eb3[0];
#pragma unroll
    for (int j = 0; j < HH; ++j)
        lg = fmaf(fmaxf(acc[j] + eb2[j], 0.f), ew3[j], lg);
    energy_out[e] = 1.f / (1.f + expf(-2.f * lg));
}

// ---------------------------------------------------------------------------
// kF: thread-per-node — IDENTICAL structure to R4, but __launch_bounds__(128,4)
// (the exact config that gave kE VGPR=44 / 43% occupancy) instead of (128,1)
// which let the allocator bloat registers and kill latency hiding.
// ---------------------------------------------------------------------------
__global__ __launch_bounds__(128, 4) void kF(const float* __restrict__ ws,
                                             const float* __restrict__ dw1,
                                             const float* __restrict__ db1,
                                             const float* __restrict__ dw2,
                                             const float* __restrict__ db2,
                                             const float* __restrict__ dw3,
                                             const float* __restrict__ db3,
                                             float* __restrict__ out) {
    int n = blockIdx.x * 128 + threadIdx.x;
    if (n >= NN) return;
    const float* energy = out + 2 * (size_t)NKE;

    float ev[KK];
    float dh = 0.f;
#pragma unroll
    for (int j = 0; j < KK; ++j) {
        ev[j] = energy[(size_t)n * KK + j];
        dh += ev[j];
    }

    const float* XC = ws + 2 * (size_t)NN * HH + (size_t)n * HH;
    const float* w1l = dw1 + DD * HH;

    float acc[HH];
#pragma unroll
    for (int j = 0; j < HH; ++j) acc[j] = 0.f;

    float4 c4 = *(const float4*)XC;
#pragma unroll 1
    for (int i4 = 0; i4 < HH / 4; ++i4) {
        float4 c = c4;
        int nx = (i4 + 1 < HH / 4) ? (i4 + 1) : i4;
        c4 = *(const float4*)(XC + nx * 4);
        float cv[4] = {c.x, c.y, c.z, c.w};
#pragma unroll
        for (int m = 0; m < 4; ++m) {
            int k = i4 * 4 + m;
            float g = fmaxf(cv[m] + dh * w1l[k] + db1[k], 0.f);
            const float* wr = dw2 + k * HH;
#pragma unroll
            for (int j4 = 0; j4 < 16; ++j4) {
                float4 w = *(const float4*)(wr + j4 * 4);
                acc[j4 * 4 + 0] = fmaf(g, w.x, acc[j4 * 4 + 0]);
                acc[j4 * 4 + 1] = fmaf(g, w.y, acc[j4 * 4 + 1]);
                acc[j4 * 4 + 2] = fmaf(g, w.z, acc[j4 * 4 + 2]);
                acc[j4 * 4 + 3] = fmaf(g, w.w, acc[j4 * 4 + 3]);
            }
        }
    }
    float kraw = db3[0];
#pragma unroll
    for (int j = 0; j < HH; ++j)
        kraw = fmaf(fmaxf(acc[j] + db2[j], 0.f), dw3[j], kraw);

    float kcont = 2.f + 13.f / (1.f + expf(-kraw));
    out[3 * (size_t)NKE + n] = kcont;

    // register-resident sort of (energy desc, idx asc), 16-wide network
    float se[16];
    int si[16];
#pragma unroll
    for (int j = 0; j < KK; ++j) { se[j] = ev[j]; si[j] = j; }
    se[15] = -1.f; si[15] = 15;

#pragma unroll
    for (int p = 1; p < 16; p <<= 1) {
#pragma unroll
        for (int k = p; k >= 1; k >>= 1) {
#pragma unroll
            for (int j = k & (p - 1); j + k < 16; j += 2 * k) {
#pragma unroll
                for (int i = 0; i < k; ++i) {
                    int a = i + j, b = i + j + k;
                    if (b < 16 && (a / (2 * p)) == (b / (2 * p))) {
                        bool sw = (se[b] > se[a]) ||
                                  (se[b] == se[a] && si[b] < si[a]);
                        float ea = sw ? se[b] : se[a];
                        float eb = sw ? se[a] : se[b];
                        int ia = sw ? si[b] : si[a];
                        int ib = sw ? si[a] : si[b];
                        se[a] = ea; se[b] = eb; si[a] = ia; si[b] = ib;
                    }
                }
            }
        }
    }

    float kint = rintf(kcont);
    kint = fminf(fmaxf(kint, 2.f), 15.f);

    float wsrt[KK];
    float denom = 0.f;
#pragma unroll
    for (int r = 0; r < KK; ++r) {
        float sel = ((float)(r + 1) <= kint) ? 1.f : 0.f;
        float wvv = se[r] * sel;
        wsrt[r] = wvv;
        denom += wvv;
    }
    denom = fmaxf(denom, 1e-12f);

#pragma unroll
    for (int r = 0; r < KK; ++r) {
        float sel = ((float)(r + 1) <= kint) ? 1.f : 0.f;
        int j0 = si[r];
        out[(size_t)NKE + (size_t)n * KK + j0] = sel;     // edge_gate
        out[(size_t)n * KK + j0] = wsrt[r] / denom;       // edge_weight
    }
}

extern "C" void kernel_launch(void* const* d_in, const int* in_sizes, int n_in,
                              void* d_out, int out_size, void* d_ws, size_t ws_size,
                              hipStream_t stream) {
    const float* x   = (const float*)d_in[0];
    const int*   ei  = (const int*)d_in[1];
    const float* ed  = (const float*)d_in[2];
    const float* ew1 = (const float*)d_in[3];
    const float* eb1 = (const float*)d_in[4];
    const float* ew2 = (const float*)d_in[5];
    const float* eb2 = (const float*)d_in[6];
    const float* ew3 = (const float*)d_in[7];
    const float* eb3 = (const float*)d_in[8];
    const float* dw1 = (const float*)d_in[9];
    const float* db1 = (const float*)d_in[10];
    const float* dw2 = (const float*)d_in[11];
    const float* db2 = (const float*)d_in[12];
    const float* dw3 = (const float*)d_in[13];
    const float* db3 = (const float*)d_in[14];
    float* out = (float*)d_out;
    float* ws  = (float*)d_ws;

    hipLaunchKernelGGL(kP, dim3((NN + 31) / 32), dim3(256), 0, stream,
                       x, ew1, dw1, ws);
    hipLaunchKernelGGL(kE, dim3((NKE + 127) / 128), dim3(128), 0, stream,
                       ei, ed, ws, ew1, eb1, ew2, eb2, ew3, eb3,
                       out + 2 * (size_t)NKE);
    hipLaunchKernelGGL(kF, dim3((NN + 127) / 128), dim3(128), 0, stream,
                       ws, dw1, db1, dw2, db2, dw3, db3, out);
}